// Round 8
// baseline (256.001 us; speedup 1.0000x reference)
//
#include <hip/hip_runtime.h>
#include <hip/hip_bf16.h>

#define N_NODES 50000
#define N_EDGES 819200
#define NUM_RELS 8
#define EPR (N_EDGES / NUM_RELS) /* 102400 */
#define N_HEADS 4
#define IN_FEAT 256
#define OUT_FEAT 128
#define HEAD_DIM 32
#define NB_SCAN ((N_NODES + 255) / 256) /* 196 */

typedef __attribute__((ext_vector_type(8))) __bf16 bf16x8;
typedef __attribute__((ext_vector_type(4))) __bf16 bf16x4;
typedef __attribute__((ext_vector_type(4))) float f32x4;

// ---- workspace layout (float units) ----
#define SZ_FEAT ((size_t)NUM_RELS * N_NODES * OUT_FEAT)
#define SZ_EL ((size_t)NUM_RELS * N_NODES * N_HEADS)
#define SZ_WB ((size_t)IN_FEAT * 64) /* wbt (8192 floats) + wbl (8192 floats) */
#define SZ_WT ((size_t)NUM_RELS * OUT_FEAT * IN_FEAT / 2)
#define OFF_FEAT ((size_t)0)
#define OFF_EL (OFF_FEAT + SZ_FEAT)
#define OFF_ER (OFF_EL + SZ_EL)
#define OFF_WB (OFF_ER + SZ_EL)
#define OFF_WT (OFF_WB + SZ_WB)
#define OFF_INT (OFF_WT + SZ_WT)
#define IOFF_CNT ((size_t)0)
#define IOFF_PTR ((size_t)N_NODES)
#define IOFF_CUR ((size_t)2 * N_NODES)
#define IOFF_BSUM ((size_t)3 * N_NODES)
#define IOFF_SPAY ((size_t)3 * N_NODES + 256)

__device__ __forceinline__ void gload16(const void* g, void* l) {
    __builtin_amdgcn_global_load_lds(
        (const __attribute__((address_space(1))) unsigned int*)g,
        (__attribute__((address_space(3))) unsigned int*)l, 16, 0, 0);
}

// weights -> per-(r,kc,ks) 8KB LDS images: [128 brow][4 slots of 16B],
// slot s holds k-octet q = s ^ ((brow>>1)&3); k = kc*64+ks*32+q*8
__global__ void k_cvtw(const float* __restrict__ cw, __bf16* __restrict__ wtl) {
    int tid = blockIdx.x * blockDim.x + threadIdx.x;
    if (tid >= 32768) return;
    int s = tid & 3, brow = (tid >> 2) & 127, ks = (tid >> 9) & 1, kc = (tid >> 10) & 3, r = tid >> 12;
    int q = s ^ ((brow >> 1) & 3);
    int k0 = kc * 64 + ks * 32 + q * 8;
    int h = brow >> 5, d = brow & 31;
    const float* src = cw + ((size_t)(r * N_HEADS + h) * IN_FEAT + k0) * HEAD_DIM + d;
    bf16x8 v;
#pragma unroll
    for (int j = 0; j < 8; ++j) v[j] = (__bf16)src[j * HEAD_DIM];
    *(bf16x8*)(wtl + (size_t)tid * 8) = v;
}

// folded attention vectors, transposed bf16: wbt[col][k], col = side*32+r*4+h
__global__ void k_wboth(const float* __restrict__ cw, const float* __restrict__ al,
                        const float* __restrict__ ar, __bf16* __restrict__ wbt) {
    int tid = blockIdx.x * blockDim.x + threadIdx.x;
    if (tid >= IN_FEAT * 64) return;
    int col = tid >> 8, i = tid & 255;
    int side = col >> 5, r = (col >> 2) & 7, h = col & 3;
    const float* av = (side ? ar : al) + (size_t)(r * N_HEADS + h) * HEAD_DIM;
    const float* cwp = cw + ((size_t)(r * N_HEADS + h) * IN_FEAT + i) * HEAD_DIM;
    float s = 0.f;
#pragma unroll
    for (int d = 0; d < HEAD_DIM; ++d) s += cwp[d] * av[d];
    wbt[(size_t)col * IN_FEAT + i] = (__bf16)s;
}

// wbt -> per-(kc,ks) 4KB images: [64 brow][4 slots], q = s ^ ((brow>>1)&3)
__global__ void k_wbimg(const __bf16* __restrict__ wbt, __bf16* __restrict__ wbl) {
    int tid = blockIdx.x * blockDim.x + threadIdx.x;
    if (tid >= 2048) return;
    int s = tid & 3, brow = (tid >> 2) & 63, ks = (tid >> 8) & 1, kc = tid >> 9;
    int q = s ^ ((brow >> 1) & 3);
    int k0 = kc * 64 + ks * 32 + q * 8;
    bf16x8 v = *(const bf16x8*)(wbt + (size_t)brow * IN_FEAT + k0);
    *(bf16x8*)(wbl + (size_t)tid * 8) = v;
}

// Fused transform, 64-node tile for 3 blocks/CU TLP:
// A staged once (fp32->bf16, swizzled ds_write), 64 GEMM items (r,kc,ks)
// + 8 el/er items, double-buffered B via global_load_lds + counted vmcnt.
__global__ __launch_bounds__(256, 3) void k_fused(const float* __restrict__ x,
                                                  const __bf16* __restrict__ wtl,
                                                  const __bf16* __restrict__ wbl,
                                                  __bf16* __restrict__ featb,
                                                  float* __restrict__ el,
                                                  float* __restrict__ er) {
    __shared__ __align__(16) unsigned char sA[32768]; // [64 rows][512B] swizzled
    __shared__ __align__(16) unsigned char sB[16384]; // 2 x 8KB chunk buffers
    const int t = threadIdx.x, lane = t & 63, w = t >> 6;
    const int wr = w >> 1, wc = w & 1;
    const int n0 = blockIdx.x * 64;

    // ---- prologue: issue B chunk 0 ----
#pragma unroll
    for (int i = 0; i < 2; ++i)
        gload16((const char*)wtl + i * 4096 + w * 1024 + lane * 16, sB + i * 4096 + w * 1024);

    // ---- stage A once: 64 rows x 256 k, fp32 -> bf16, swizzled ds_write ----
#pragma unroll
    for (int i = 0; i < 16; ++i) {
        int flat = i * 256 + t;   // 0..4095 float4 units
        int row = flat >> 6;      // 0..63
        int kq = flat & 63;       // k = kq*4
        int n = n0 + row;
        if (n >= N_NODES) n = N_NODES - 1;
        float4 v = *(const float4*)(x + (size_t)n * IN_FEAT + kq * 4);
        bf16x4 hv;
        hv[0] = (__bf16)v.x; hv[1] = (__bf16)v.y; hv[2] = (__bf16)v.z; hv[3] = (__bf16)v.w;
        int sg = kq >> 1;
        int slot = (sg & ~7) | ((sg & 7) ^ (row & 7));
        *(bf16x4*)(sA + row * 512 + slot * 16 + (kq & 1) * 8) = hv;
    }
    __syncthreads();

    f32x4 acc[2][4];
#pragma unroll
    for (int i = 0; i < 2; ++i)
#pragma unroll
        for (int j = 0; j < 4; ++j) acc[i][j] = (f32x4){0.f, 0.f, 0.f, 0.f};

    // ---- 64 GEMM items ----
    for (int item = 0; item < 64; ++item) {
        const int buf = item & 1;
        if (item < 63) {
            const char* ch = (const char*)wtl + (size_t)(item + 1) * 8192;
#pragma unroll
            for (int i = 0; i < 2; ++i)
                gload16(ch + i * 4096 + w * 1024 + lane * 16, sB + (buf ^ 1) * 8192 + i * 4096 + w * 1024);
            asm volatile("s_waitcnt vmcnt(2)" ::: "memory");
        } else {
            gload16((const char*)wbl + w * 1024 + lane * 16, sB + (buf ^ 1) * 8192 + w * 1024);
            asm volatile("s_waitcnt vmcnt(1)" ::: "memory");
        }
        __builtin_amdgcn_s_barrier();
        __builtin_amdgcn_sched_barrier(0);

        const int r = item >> 3, kc = (item >> 1) & 3, ks = item & 1;
        bf16x8 af[2], bg[4];
#pragma unroll
        for (int rb = 0; rb < 2; ++rb) {
            int row = wr * 32 + rb * 16 + (lane & 15);
            int slot = kc * 8 + ((ks * 4 + (lane >> 4)) ^ (row & 7));
            af[rb] = *(const bf16x8*)(sA + row * 512 + slot * 16);
        }
#pragma unroll
        for (int cb = 0; cb < 4; ++cb) {
            int brow = wc * 64 + cb * 16 + (lane & 15);
            int s = (lane >> 4) ^ ((brow >> 1) & 3);
            bg[cb] = *(const bf16x8*)(sB + buf * 8192 + brow * 64 + s * 16);
        }
#pragma unroll
        for (int rb = 0; rb < 2; ++rb)
#pragma unroll
            for (int cb = 0; cb < 4; ++cb)
                acc[rb][cb] = __builtin_amdgcn_mfma_f32_16x16x32_bf16(af[rb], bg[cb], acc[rb][cb], 0, 0, 0);

        if ((item & 7) == 7) { // epilogue rel r; C map col=lane&15, row=(lane>>4)*4+q
#pragma unroll
            for (int rb = 0; rb < 2; ++rb)
#pragma unroll
                for (int q = 0; q < 4; ++q) {
                    int rowi = wr * 32 + rb * 16 + (lane >> 4) * 4 + q;
                    int n = n0 + rowi;
                    if (n < N_NODES) {
                        __bf16* fp = featb + ((size_t)r * N_NODES + n) * OUT_FEAT + wc * 64 + (lane & 15);
#pragma unroll
                        for (int cb = 0; cb < 4; ++cb) fp[cb * 16] = (__bf16)acc[rb][cb][q];
                    }
                }
#pragma unroll
            for (int i = 0; i < 2; ++i)
#pragma unroll
                for (int j = 0; j < 4; ++j) acc[i][j] = (f32x4){0.f, 0.f, 0.f, 0.f};
        }
        asm volatile("" ::: "memory");
        __builtin_amdgcn_s_barrier();
    }

    // ---- 8 el/er items ----
    f32x4 acc2[2][2];
#pragma unroll
    for (int i = 0; i < 2; ++i)
#pragma unroll
        for (int j = 0; j < 2; ++j) acc2[i][j] = (f32x4){0.f, 0.f, 0.f, 0.f};

    for (int e = 0; e < 8; ++e) {
        const int buf = e & 1;
        if (e < 7) {
            gload16((const char*)wbl + (size_t)(e + 1) * 4096 + w * 1024 + lane * 16,
                    sB + (buf ^ 1) * 8192 + w * 1024);
            asm volatile("s_waitcnt vmcnt(1)" ::: "memory");
        } else {
            asm volatile("s_waitcnt vmcnt(0)" ::: "memory");
        }
        __builtin_amdgcn_s_barrier();
        __builtin_amdgcn_sched_barrier(0);

        const int kc = e >> 1, ks = e & 1;
        bf16x8 af[2], bg[2];
#pragma unroll
        for (int rb = 0; rb < 2; ++rb) {
            int row = wr * 32 + rb * 16 + (lane & 15);
            int slot = kc * 8 + ((ks * 4 + (lane >> 4)) ^ (row & 7));
            af[rb] = *(const bf16x8*)(sA + row * 512 + slot * 16);
        }
#pragma unroll
        for (int cb = 0; cb < 2; ++cb) {
            int brow = wc * 32 + cb * 16 + (lane & 15);
            int s = (lane >> 4) ^ ((brow >> 1) & 3);
            bg[cb] = *(const bf16x8*)(sB + buf * 8192 + brow * 64 + s * 16);
        }
#pragma unroll
        for (int rb = 0; rb < 2; ++rb)
#pragma unroll
            for (int cb = 0; cb < 2; ++cb)
                acc2[rb][cb] = __builtin_amdgcn_mfma_f32_16x16x32_bf16(af[rb], bg[cb], acc2[rb][cb], 0, 0, 0);
        asm volatile("" ::: "memory");
        __builtin_amdgcn_s_barrier();
    }
    // el/er epilogue
#pragma unroll
    for (int rb = 0; rb < 2; ++rb)
#pragma unroll
        for (int q = 0; q < 4; ++q) {
            int n = n0 + wr * 32 + rb * 16 + (lane >> 4) * 4 + q;
            if (n < N_NODES) {
#pragma unroll
                for (int cb = 0; cb < 2; ++cb) {
                    int c = wc * 32 + cb * 16 + (lane & 15);
                    int side = c >> 5, rr = (c >> 2) & 7, h = c & 3;
                    float* dst = side ? er : el;
                    dst[((size_t)rr * N_NODES + n) * N_HEADS + h] = acc2[rb][cb][q];
                }
            }
        }
}

// ---- CSR build ----
__global__ void k_hist(const int* __restrict__ col, int* __restrict__ cnt) {
    int e = blockIdx.x * blockDim.x + threadIdx.x;
    if (e < N_EDGES) atomicAdd(cnt + col[e], 1);
}

__global__ __launch_bounds__(256) void k_scanA(const int* __restrict__ cnt,
                                               int* __restrict__ excl,
                                               int* __restrict__ bsum) {
    __shared__ int s[256];
    int i = blockIdx.x * 256 + threadIdx.x;
    int v = (i < N_NODES) ? cnt[i] : 0;
    s[threadIdx.x] = v;
    __syncthreads();
#pragma unroll
    for (int off = 1; off < 256; off <<= 1) {
        int t = (threadIdx.x >= off) ? s[threadIdx.x - off] : 0;
        __syncthreads();
        s[threadIdx.x] += t;
        __syncthreads();
    }
    if (i < N_NODES) excl[i] = s[threadIdx.x] - v;
    if (threadIdx.x == 255) bsum[blockIdx.x] = s[255];
}

__global__ __launch_bounds__(256) void k_scanB(int* __restrict__ bsum) {
    __shared__ int s[256];
    int v = (threadIdx.x < NB_SCAN) ? bsum[threadIdx.x] : 0;
    s[threadIdx.x] = v;
    __syncthreads();
#pragma unroll
    for (int off = 1; off < 256; off <<= 1) {
        int t = (threadIdx.x >= off) ? s[threadIdx.x - off] : 0;
        __syncthreads();
        s[threadIdx.x] += t;
        __syncthreads();
    }
    bsum[threadIdx.x] = s[threadIdx.x] - v;
}

__global__ __launch_bounds__(256) void k_scanC(int* __restrict__ ptr,
                                               int* __restrict__ cursor,
                                               const int* __restrict__ bsum) {
    int i = blockIdx.x * 256 + threadIdx.x;
    if (i >= N_NODES) return;
    int p = ptr[i] + bsum[blockIdx.x];
    ptr[i] = p;
    cursor[i] = p;
}

__global__ void k_scatter(const int* __restrict__ row, const int* __restrict__ col,
                          int* __restrict__ cursor, int* __restrict__ spay) {
    int e = blockIdx.x * blockDim.x + threadIdx.x;
    if (e >= N_EDGES) return;
    int c = col[e];
    int pos = atomicAdd(cursor + c, 1);
    spay[pos] = row[e] | ((e / EPR) << 20);
}

// pull-aggregation, bf16 feat gather, 4-deep explicit pipeline
__global__ __launch_bounds__(256) void k_agg(const int* __restrict__ ptr,
                                             const int* __restrict__ cnt,
                                             const int* __restrict__ spay,
                                             const float* __restrict__ el,
                                             const float* __restrict__ er,
                                             const __bf16* __restrict__ featb,
                                             const float* __restrict__ bias,
                                             float* __restrict__ out) {
    const int wv = threadIdx.x >> 6, lane = threadIdx.x & 63;
    const int n = blockIdx.x * 4 + wv;
    if (n >= N_NODES) return;
    const int start = ptr[n], len = cnt[n];
    const int h = lane >> 4;
    float accx = 0.f, accy = 0.f, den = 0.f;
    int j = 0;
    for (; j + 4 <= len; j += 4) {
        int p[4];
#pragma unroll
        for (int u = 0; u < 4; ++u) p[u] = spay[start + j + u];
        float w[4], vx[4], vy[4];
#pragma unroll
        for (int u = 0; u < 4; ++u) {
            int rw = p[u] & 0xFFFFF, r = p[u] >> 20;
            size_t rb = (size_t)r * N_NODES;
            float s = el[(rb + rw) * N_HEADS + h] + er[(rb + n) * N_HEADS + h];
            s = s > 0.f ? s : 0.2f * s;
            w[u] = __expf(s);
            ushort2 raw = *(const ushort2*)(featb + (rb + rw) * OUT_FEAT + lane * 2);
            vx[u] = __uint_as_float((unsigned)raw.x << 16);
            vy[u] = __uint_as_float((unsigned)raw.y << 16);
        }
#pragma unroll
        for (int u = 0; u < 4; ++u) {
            accx += w[u] * vx[u];
            accy += w[u] * vy[u];
            den += w[u];
        }
    }
    for (; j < len; ++j) {
        int p = spay[start + j];
        int rw = p & 0xFFFFF, r = p >> 20;
        size_t rb = (size_t)r * N_NODES;
        float s = el[(rb + rw) * N_HEADS + h] + er[(rb + n) * N_HEADS + h];
        s = s > 0.f ? s : 0.2f * s;
        float w = __expf(s);
        ushort2 raw = *(const ushort2*)(featb + (rb + rw) * OUT_FEAT + lane * 2);
        accx += w * __uint_as_float((unsigned)raw.x << 16);
        accy += w * __uint_as_float((unsigned)raw.y << 16);
        den += w;
    }
    float inv = (len > 0) ? 1.f / den : 0.f;
    int o = lane * 2;
    float2 res;
    res.x = accx * inv + bias[o];
    res.y = accy * inv + bias[o + 1];
    *(float2*)(out + (size_t)n * OUT_FEAT + o) = res;
}

extern "C" void kernel_launch(void* const* d_in, const int* in_sizes, int n_in,
                              void* d_out, int out_size, void* d_ws, size_t ws_size,
                              hipStream_t stream) {
    const float* x = (const float*)d_in[0];
    const float* cw = (const float*)d_in[1];
    const float* al = (const float*)d_in[2];
    const float* ar = (const float*)d_in[3];
    const float* bias = (const float*)d_in[4];
    const int* row = (const int*)d_in[5];
    const int* col = (const int*)d_in[6];
    float* out = (float*)d_out;
    float* ws = (float*)d_ws;

    __bf16* featb = (__bf16*)(ws + OFF_FEAT);
    float* el = ws + OFF_EL;
    float* er = ws + OFF_ER;
    __bf16* wbt = (__bf16*)(ws + OFF_WB);
    __bf16* wbl = (__bf16*)(ws + OFF_WB + 8192);
    __bf16* wtl = (__bf16*)(ws + OFF_WT);
    int* iw = (int*)(ws + OFF_INT);
    int* cnt = iw + IOFF_CNT;
    int* ptr = iw + IOFF_PTR;
    int* cur = iw + IOFF_CUR;
    int* bsum = iw + IOFF_BSUM;
    int* spay = iw + IOFF_SPAY;

    hipMemsetAsync(cnt, 0, N_NODES * sizeof(int), stream);

    k_cvtw<<<128, 256, 0, stream>>>(cw, wtl);
    k_wboth<<<(IN_FEAT * 64 + 255) / 256, 256, 0, stream>>>(cw, al, ar, wbt);
    k_wbimg<<<8, 256, 0, stream>>>(wbt, wbl);
    k_fused<<<(N_NODES + 63) / 64, 256, 0, stream>>>(x, wtl, wbl, featb, el, er);

    k_hist<<<(N_EDGES + 255) / 256, 256, 0, stream>>>(col, cnt);
    k_scanA<<<NB_SCAN, 256, 0, stream>>>(cnt, ptr, bsum);
    k_scanB<<<1, 256, 0, stream>>>(bsum);
    k_scanC<<<NB_SCAN, 256, 0, stream>>>(ptr, cur, bsum);
    k_scatter<<<(N_EDGES + 255) / 256, 256, 0, stream>>>(row, col, cur, spay);

    k_agg<<<(N_NODES + 3) / 4, 256, 0, stream>>>(ptr, cnt, spay, el, er, featb, bias, out);
}

// Round 9
// 240.405 us; speedup vs baseline: 1.0649x; 1.0649x over previous
//
#include <hip/hip_runtime.h>
#include <hip/hip_bf16.h>

#define N_NODES 50000
#define N_EDGES 819200
#define NUM_RELS 8
#define EPR (N_EDGES / NUM_RELS) /* 102400 */
#define N_HEADS 4
#define IN_FEAT 256
#define OUT_FEAT 128
#define HEAD_DIM 32
#define NB_SCAN ((N_NODES + 255) / 256) /* 196 */

typedef __attribute__((ext_vector_type(8))) __bf16 bf16x8;
typedef __attribute__((ext_vector_type(4))) __bf16 bf16x4;
typedef __attribute__((ext_vector_type(4))) float f32x4;

// ---- workspace layout (float units) ----
#define SZ_FEAT ((size_t)NUM_RELS * N_NODES * OUT_FEAT)
#define SZ_EL ((size_t)NUM_RELS * N_NODES * N_HEADS)
#define SZ_WB ((size_t)IN_FEAT * 64) /* wbt (8192 floats) + wbg (8192 floats) */
#define SZ_WT ((size_t)NUM_RELS * OUT_FEAT * IN_FEAT / 2)
#define OFF_FEAT ((size_t)0)
#define OFF_EL (OFF_FEAT + SZ_FEAT)
#define OFF_ER (OFF_EL + SZ_EL)
#define OFF_WB (OFF_ER + SZ_EL)
#define OFF_WT (OFF_WB + SZ_WB)
#define OFF_INT (OFF_WT + SZ_WT)
#define IOFF_CNT ((size_t)0)
#define IOFF_PTR ((size_t)N_NODES)
#define IOFF_CUR ((size_t)2 * N_NODES)
#define IOFF_BSUM ((size_t)3 * N_NODES)
#define IOFF_SPAY ((size_t)3 * N_NODES + 256)

// weights -> fragment-ordered image: frag idx = (((r*4+kc)*2+ks)*128 + brow)*4 + oct
// frag holds bf16 k-octet: k = kc*64+ks*32+oct*8, output brow = h*32+d
__global__ void k_cvtw(const float* __restrict__ cw, __bf16* __restrict__ wtg) {
    int tid = blockIdx.x * blockDim.x + threadIdx.x;
    if (tid >= 32768) return;
    int oct = tid & 3, brow = (tid >> 2) & 127, ks = (tid >> 9) & 1, kc = (tid >> 10) & 3, r = tid >> 12;
    int k0 = kc * 64 + ks * 32 + oct * 8;
    int h = brow >> 5, d = brow & 31;
    const float* src = cw + ((size_t)(r * N_HEADS + h) * IN_FEAT + k0) * HEAD_DIM + d;
    bf16x8 v;
#pragma unroll
    for (int j = 0; j < 8; ++j) v[j] = (__bf16)src[j * HEAD_DIM];
    *(bf16x8*)(wtg + (size_t)tid * 8) = v;
}

// folded attention vectors, transposed bf16: wbt[col][k], col = side*32+r*4+h
__global__ void k_wboth(const float* __restrict__ cw, const float* __restrict__ al,
                        const float* __restrict__ ar, __bf16* __restrict__ wbt) {
    int tid = blockIdx.x * blockDim.x + threadIdx.x;
    if (tid >= IN_FEAT * 64) return;
    int col = tid >> 8, i = tid & 255;
    int side = col >> 5, r = (col >> 2) & 7, h = col & 3;
    const float* av = (side ? ar : al) + (size_t)(r * N_HEADS + h) * HEAD_DIM;
    const float* cwp = cw + ((size_t)(r * N_HEADS + h) * IN_FEAT + i) * HEAD_DIM;
    float s = 0.f;
#pragma unroll
    for (int d = 0; d < HEAD_DIM; ++d) s += cwp[d] * av[d];
    wbt[(size_t)col * IN_FEAT + i] = (__bf16)s;
}

// wbt -> fragment image: idx = ((kc*2+ks)*64 + brow)*4 + oct
__global__ void k_wbg(const __bf16* __restrict__ wbt, __bf16* __restrict__ wbg) {
    int tid = blockIdx.x * blockDim.x + threadIdx.x;
    if (tid >= 2048) return;
    int oct = tid & 3, brow = (tid >> 2) & 63, ks = (tid >> 8) & 1, kc = tid >> 9;
    int k0 = kc * 64 + ks * 32 + oct * 8;
    bf16x8 v = *(const bf16x8*)(wbt + (size_t)brow * IN_FEAT + k0);
    *(bf16x8*)(wbg + (size_t)tid * 8) = v;
}

__device__ __forceinline__ void loadB(bf16x8 (&dst)[8], const __bf16* __restrict__ wtg,
                                      int r, int kc, int wc, int lane) {
#pragma unroll
    for (int ks = 0; ks < 2; ++ks)
#pragma unroll
        for (int cb = 0; cb < 4; ++cb)
            dst[ks * 4 + cb] = *(const bf16x8*)(wtg +
                ((size_t)((((r * 4 + kc) * 2 + ks) * 128) + wc * 64 + cb * 16 + (lane & 15)) * 4 + (lane >> 4)) * 8);
}

__device__ __forceinline__ void loadB2(bf16x8 (&dst)[4], const __bf16* __restrict__ wbg,
                                       int kc, int wc, int lane) {
#pragma unroll
    for (int ks = 0; ks < 2; ++ks)
#pragma unroll
        for (int cb = 0; cb < 2; ++cb)
            dst[ks * 2 + cb] = *(const bf16x8*)(wbg +
                ((size_t)(((kc * 2 + ks) * 64) + wc * 32 + cb * 16 + (lane & 15)) * 4 + (lane >> 4)) * 8);
}

__device__ __forceinline__ void compK(f32x4 (&acc)[4][4], const unsigned char* sA,
                                      const bf16x8 (&bg)[8], int kc, int wr, int lane) {
#pragma unroll
    for (int ks = 0; ks < 2; ++ks) {
        bf16x8 af[4];
#pragma unroll
        for (int rb = 0; rb < 4; ++rb) {
            int rowa = wr * 64 + rb * 16 + (lane & 15);
            int slot = kc * 8 + ((ks * 4 + (lane >> 4)) ^ (rowa & 7));
            af[rb] = *(const bf16x8*)(sA + rowa * 512 + slot * 16);
        }
#pragma unroll
        for (int rb = 0; rb < 4; ++rb)
#pragma unroll
            for (int cb = 0; cb < 4; ++cb)
                acc[rb][cb] = __builtin_amdgcn_mfma_f32_16x16x32_bf16(af[rb], bg[ks * 4 + cb], acc[rb][cb], 0, 0, 0);
    }
}

__device__ __forceinline__ void compK2(f32x4 (&acc2)[4][2], const unsigned char* sA,
                                       const bf16x8 (&bg)[4], int kc, int wr, int lane) {
#pragma unroll
    for (int ks = 0; ks < 2; ++ks) {
        bf16x8 af[4];
#pragma unroll
        for (int rb = 0; rb < 4; ++rb) {
            int rowa = wr * 64 + rb * 16 + (lane & 15);
            int slot = kc * 8 + ((ks * 4 + (lane >> 4)) ^ (rowa & 7));
            af[rb] = *(const bf16x8*)(sA + rowa * 512 + slot * 16);
        }
#pragma unroll
        for (int rb = 0; rb < 4; ++rb)
#pragma unroll
            for (int cb = 0; cb < 2; ++cb)
                acc2[rb][cb] = __builtin_amdgcn_mfma_f32_16x16x32_bf16(af[rb], bg[ks * 2 + cb], acc2[rb][cb], 0, 0, 0);
    }
}

// Fused transform: A in LDS (staged once, ONE barrier), B streamed global->VGPR
// (no barriers in the main loop). 128-node tile, 4 waves 2x2.
__global__ __launch_bounds__(256) void k_fused(const float* __restrict__ x,
                                               const __bf16* __restrict__ wtg,
                                               const __bf16* __restrict__ wbg,
                                               __bf16* __restrict__ featb,
                                               float* __restrict__ el,
                                               float* __restrict__ er) {
    __shared__ __align__(16) unsigned char sA[65536]; // [128 rows][512B] swizzled
    const int t = threadIdx.x, lane = t & 63, w = t >> 6;
    const int wr = w >> 1, wc = w & 1;
    const int n0 = blockIdx.x * 128;

    // ---- stage A once: 128 rows x 256 k, fp32 -> bf16, swizzled ds_write ----
#pragma unroll 8
    for (int i = 0; i < 32; ++i) {
        int flat = i * 256 + t;   // 0..8191 float4 units
        int row = flat >> 6;      // 0..127
        int kq = flat & 63;       // k = kq*4
        int n = n0 + row;
        if (n >= N_NODES) n = N_NODES - 1;
        float4 v = *(const float4*)(x + (size_t)n * IN_FEAT + kq * 4);
        bf16x4 hv;
        hv[0] = (__bf16)v.x; hv[1] = (__bf16)v.y; hv[2] = (__bf16)v.z; hv[3] = (__bf16)v.w;
        int sg = kq >> 1;
        int slot = (sg & ~7) | ((sg & 7) ^ (row & 7));
        *(bf16x4*)(sA + row * 512 + slot * 16 + (kq & 1) * 8) = hv;
    }
    __syncthreads();

    // ---- 8 relation passes, B double-buffered in registers ----
    bf16x8 bgA[8], bgB[8];
    for (int r = 0; r < NUM_RELS; ++r) {
        f32x4 acc[4][4];
#pragma unroll
        for (int i = 0; i < 4; ++i)
#pragma unroll
            for (int j = 0; j < 4; ++j) acc[i][j] = (f32x4){0.f, 0.f, 0.f, 0.f};

        loadB(bgA, wtg, r, 0, wc, lane);
        loadB(bgB, wtg, r, 1, wc, lane);
        compK(acc, sA, bgA, 0, wr, lane);
        loadB(bgA, wtg, r, 2, wc, lane);
        compK(acc, sA, bgB, 1, wr, lane);
        loadB(bgB, wtg, r, 3, wc, lane);
        compK(acc, sA, bgA, 2, wr, lane);
        compK(acc, sA, bgB, 3, wr, lane);

        // epilogue rel r (C map: col=lane&15, row=(lane>>4)*4+q)
#pragma unroll
        for (int rb = 0; rb < 4; ++rb)
#pragma unroll
            for (int q = 0; q < 4; ++q) {
                int rowi = wr * 64 + rb * 16 + (lane >> 4) * 4 + q;
                int n = n0 + rowi;
                if (n < N_NODES) {
                    __bf16* fp = featb + ((size_t)r * N_NODES + n) * OUT_FEAT + wc * 64 + (lane & 15);
#pragma unroll
                    for (int cb = 0; cb < 4; ++cb) fp[cb * 16] = (__bf16)acc[rb][cb][q];
                }
            }
    }

    // ---- el/er pass ----
    f32x4 acc2[4][2];
#pragma unroll
    for (int i = 0; i < 4; ++i)
#pragma unroll
        for (int j = 0; j < 2; ++j) acc2[i][j] = (f32x4){0.f, 0.f, 0.f, 0.f};

    bf16x8 cgA[4], cgB[4];
    loadB2(cgA, wbg, 0, wc, lane);
    loadB2(cgB, wbg, 1, wc, lane);
    compK2(acc2, sA, cgA, 0, wr, lane);
    loadB2(cgA, wbg, 2, wc, lane);
    compK2(acc2, sA, cgB, 1, wr, lane);
    loadB2(cgB, wbg, 3, wc, lane);
    compK2(acc2, sA, cgA, 2, wr, lane);
    compK2(acc2, sA, cgB, 3, wr, lane);

#pragma unroll
    for (int rb = 0; rb < 4; ++rb)
#pragma unroll
        for (int q = 0; q < 4; ++q) {
            int n = n0 + wr * 64 + rb * 16 + (lane >> 4) * 4 + q;
            if (n < N_NODES) {
#pragma unroll
                for (int cb = 0; cb < 2; ++cb) {
                    int c = wc * 32 + cb * 16 + (lane & 15);
                    int side = c >> 5, rr = (c >> 2) & 7, h = c & 3;
                    float* dst = side ? er : el;
                    dst[((size_t)rr * N_NODES + n) * N_HEADS + h] = acc2[rb][cb][q];
                }
            }
        }
}

// ---- CSR build ----
__global__ void k_hist(const int* __restrict__ col, int* __restrict__ cnt) {
    int e = blockIdx.x * blockDim.x + threadIdx.x;
    if (e < N_EDGES) atomicAdd(cnt + col[e], 1);
}

__global__ __launch_bounds__(256) void k_scanA(const int* __restrict__ cnt,
                                               int* __restrict__ excl,
                                               int* __restrict__ bsum) {
    __shared__ int s[256];
    int i = blockIdx.x * 256 + threadIdx.x;
    int v = (i < N_NODES) ? cnt[i] : 0;
    s[threadIdx.x] = v;
    __syncthreads();
#pragma unroll
    for (int off = 1; off < 256; off <<= 1) {
        int t = (threadIdx.x >= off) ? s[threadIdx.x - off] : 0;
        __syncthreads();
        s[threadIdx.x] += t;
        __syncthreads();
    }
    if (i < N_NODES) excl[i] = s[threadIdx.x] - v;
    if (threadIdx.x == 255) bsum[blockIdx.x] = s[255];
}

__global__ __launch_bounds__(256) void k_scanB(int* __restrict__ bsum) {
    __shared__ int s[256];
    int v = (threadIdx.x < NB_SCAN) ? bsum[threadIdx.x] : 0;
    s[threadIdx.x] = v;
    __syncthreads();
#pragma unroll
    for (int off = 1; off < 256; off <<= 1) {
        int t = (threadIdx.x >= off) ? s[threadIdx.x - off] : 0;
        __syncthreads();
        s[threadIdx.x] += t;
        __syncthreads();
    }
    bsum[threadIdx.x] = s[threadIdx.x] - v;
}

__global__ __launch_bounds__(256) void k_scanC(int* __restrict__ ptr,
                                               int* __restrict__ cursor,
                                               const int* __restrict__ bsum) {
    int i = blockIdx.x * 256 + threadIdx.x;
    if (i >= N_NODES) return;
    int p = ptr[i] + bsum[blockIdx.x];
    ptr[i] = p;
    cursor[i] = p;
}

__global__ void k_scatter(const int* __restrict__ row, const int* __restrict__ col,
                          int* __restrict__ cursor, int* __restrict__ spay) {
    int e = blockIdx.x * blockDim.x + threadIdx.x;
    if (e >= N_EDGES) return;
    int c = col[e];
    int pos = atomicAdd(cursor + c, 1);
    spay[pos] = row[e] | ((e / EPR) << 20);
}

// pull-aggregation, bf16 feat gather, 4-deep explicit pipeline
__global__ __launch_bounds__(256) void k_agg(const int* __restrict__ ptr,
                                             const int* __restrict__ cnt,
                                             const int* __restrict__ spay,
                                             const float* __restrict__ el,
                                             const float* __restrict__ er,
                                             const __bf16* __restrict__ featb,
                                             const float* __restrict__ bias,
                                             float* __restrict__ out) {
    const int wv = threadIdx.x >> 6, lane = threadIdx.x & 63;
    const int n = blockIdx.x * 4 + wv;
    if (n >= N_NODES) return;
    const int start = ptr[n], len = cnt[n];
    const int h = lane >> 4;
    float accx = 0.f, accy = 0.f, den = 0.f;
    int j = 0;
    for (; j + 4 <= len; j += 4) {
        int p[4];
#pragma unroll
        for (int u = 0; u < 4; ++u) p[u] = spay[start + j + u];
        float w[4], vx[4], vy[4];
#pragma unroll
        for (int u = 0; u < 4; ++u) {
            int rw = p[u] & 0xFFFFF, r = p[u] >> 20;
            size_t rb = (size_t)r * N_NODES;
            float s = el[(rb + rw) * N_HEADS + h] + er[(rb + n) * N_HEADS + h];
            s = s > 0.f ? s : 0.2f * s;
            w[u] = __expf(s);
            ushort2 raw = *(const ushort2*)(featb + (rb + rw) * OUT_FEAT + lane * 2);
            vx[u] = __uint_as_float((unsigned)raw.x << 16);
            vy[u] = __uint_as_float((unsigned)raw.y << 16);
        }
#pragma unroll
        for (int u = 0; u < 4; ++u) {
            accx += w[u] * vx[u];
            accy += w[u] * vy[u];
            den += w[u];
        }
    }
    for (; j < len; ++j) {
        int p = spay[start + j];
        int rw = p & 0xFFFFF, r = p >> 20;
        size_t rb = (size_t)r * N_NODES;
        float s = el[(rb + rw) * N_HEADS + h] + er[(rb + n) * N_HEADS + h];
        s = s > 0.f ? s : 0.2f * s;
        float w = __expf(s);
        ushort2 raw = *(const ushort2*)(featb + (rb + rw) * OUT_FEAT + lane * 2);
        accx += w * __uint_as_float((unsigned)raw.x << 16);
        accy += w * __uint_as_float((unsigned)raw.y << 16);
        den += w;
    }
    float inv = (len > 0) ? 1.f / den : 0.f;
    int o = lane * 2;
    float2 res;
    res.x = accx * inv + bias[o];
    res.y = accy * inv + bias[o + 1];
    *(float2*)(out + (size_t)n * OUT_FEAT + o) = res;
}

extern "C" void kernel_launch(void* const* d_in, const int* in_sizes, int n_in,
                              void* d_out, int out_size, void* d_ws, size_t ws_size,
                              hipStream_t stream) {
    const float* x = (const float*)d_in[0];
    const float* cw = (const float*)d_in[1];
    const float* al = (const float*)d_in[2];
    const float* ar = (const float*)d_in[3];
    const float* bias = (const float*)d_in[4];
    const int* row = (const int*)d_in[5];
    const int* col = (const int*)d_in[6];
    float* out = (float*)d_out;
    float* ws = (float*)d_ws;

    __bf16* featb = (__bf16*)(ws + OFF_FEAT);
    float* el = ws + OFF_EL;
    float* er = ws + OFF_ER;
    __bf16* wbt = (__bf16*)(ws + OFF_WB);
    __bf16* wbg = (__bf16*)(ws + OFF_WB + 8192);
    __bf16* wtg = (__bf16*)(ws + OFF_WT);
    int* iw = (int*)(ws + OFF_INT);
    int* cnt = iw + IOFF_CNT;
    int* ptr = iw + IOFF_PTR;
    int* cur = iw + IOFF_CUR;
    int* bsum = iw + IOFF_BSUM;
    int* spay = iw + IOFF_SPAY;

    hipMemsetAsync(cnt, 0, N_NODES * sizeof(int), stream);

    k_cvtw<<<128, 256, 0, stream>>>(cw, wtg);
    k_wboth<<<(IN_FEAT * 64 + 255) / 256, 256, 0, stream>>>(cw, al, ar, wbt);
    k_wbg<<<8, 256, 0, stream>>>(wbt, wbg);
    k_fused<<<(N_NODES + 127) / 128, 256, 0, stream>>>(x, wtg, wbg, featb, el, er);

    k_hist<<<(N_EDGES + 255) / 256, 256, 0, stream>>>(col, cnt);
    k_scanA<<<NB_SCAN, 256, 0, stream>>>(cnt, ptr, bsum);
    k_scanB<<<1, 256, 0, stream>>>(bsum);
    k_scanC<<<NB_SCAN, 256, 0, stream>>>(ptr, cur, bsum);
    k_scatter<<<(N_EDGES + 255) / 256, 256, 0, stream>>>(row, col, cur, spay);

    k_agg<<<(N_NODES + 3) / 4, 256, 0, stream>>>(ptr, cnt, spay, el, er, featb, bias, out);
}